// Round 1
// baseline (78.975 us; speedup 1.0000x reference)
//
#include <hip/hip_runtime.h>
#include <hip/hip_bf16.h>

#define T_TOKENS 2048
#define DIM 256
#define NLEV 8
#define TILE 64
#define NTILES (T_TOKENS / TILE)   // 32

using bf16x8 = __attribute__((ext_vector_type(8))) short;
using f32x4  = __attribute__((ext_vector_type(4))) float;

__device__ __forceinline__ unsigned short f2bf(float f) {
    union { float f; unsigned u; } v; v.f = f;
    unsigned r = v.u + 0x7FFFu + ((v.u >> 16) & 1u);   // RNE
    return (unsigned short)(r >> 16);
}

// ---------------- Kernel 1: routing (exact fp32) ----------------
// wave per token: 8 levels of dot(x, w1[node]) with shuffle reduction.
__global__ __launch_bounds__(256) void route_kernel(
    const float* __restrict__ x, const float* __restrict__ w1s,
    const float* __restrict__ b1s,
    float* __restrict__ pw,   // [T][8]
    int*   __restrict__ pc)   // [T] pathcode in [256,511]
{
    int wave = threadIdx.x >> 6;
    int lane = threadIdx.x & 63;
    int t = blockIdx.x * 4 + wave;    // grid = 512 -> t < 2048

    const float4 xv = *reinterpret_cast<const float4*>(x + (size_t)t * DIM + lane * 4);
    int p = 1;
    float keep = 0.0f;
    #pragma unroll
    for (int lvl = 0; lvl < NLEV; ++lvl) {
        int node = p - 1;
        const float4 wv = *reinterpret_cast<const float4*>(w1s + (size_t)node * DIM + lane * 4);
        float s = xv.x * wv.x + xv.y * wv.y + xv.z * wv.z + xv.w * wv.w;
        #pragma unroll
        for (int off = 32; off; off >>= 1) s += __shfl_xor(s, off);
        float score = s + b1s[node];
        float a = fabsf(score);
        float g = a * 0.5f * (1.0f + erff(a * 0.70710678118654752f));  // exact GELU
        if (lane == lvl) keep = g;
        int choice = (score > 0.0f) ? 1 : 0;   // sign(0)->choice 0 matches ref
        p = 2 * p + choice;
    }
    if (lane < NLEV) pw[(size_t)t * NLEV + lane] = keep;
    if (lane == 0) pc[t] = p;
}

// ---------------- Kernel 2: counting sort by pathcode (1 block) ----------------
__global__ __launch_bounds__(256) void sort_kernel(
    const int* __restrict__ pc,
    int* __restrict__ order, int* __restrict__ spc)
{
    __shared__ int hist[256];
    __shared__ int offs[256];
    int tid = threadIdx.x;
    hist[tid] = 0;
    __syncthreads();

    int myPc[8];
    #pragma unroll
    for (int i = 0; i < 8; ++i) {
        int t = tid * 8 + i;
        myPc[i] = pc[t];
        atomicAdd(&hist[myPc[i] - 256], 1);
    }
    __syncthreads();

    if (tid < 64) {   // wave-0 exclusive scan over 256 bins (4 per lane)
        int lane = tid;
        int v0 = hist[lane * 4 + 0], v1 = hist[lane * 4 + 1];
        int v2 = hist[lane * 4 + 2], v3 = hist[lane * 4 + 3];
        int sum = v0 + v1 + v2 + v3;
        int scan = sum;
        #pragma unroll
        for (int off = 1; off < 64; off <<= 1) {
            int n = __shfl_up(scan, off);
            if (lane >= off) scan += n;
        }
        int excl = scan - sum;
        offs[lane * 4 + 0] = excl;
        offs[lane * 4 + 1] = excl + v0;
        offs[lane * 4 + 2] = excl + v0 + v1;
        offs[lane * 4 + 3] = excl + v0 + v1 + v2;
    }
    __syncthreads();

    #pragma unroll
    for (int i = 0; i < 8; ++i) {
        int t = tid * 8 + i;
        int bin = myPc[i] - 256;
        int pos = atomicAdd(&offs[bin], 1);
        order[pos] = t;
        spc[pos] = myPc[i];
    }
}

// ---------------- Kernel 3: path-weighted output via bf16 MFMA ----------------
// grid = NTILES(32) x 8 col-blocks = 256 blocks; 128 threads (2 waves).
// Each wave: 64 sorted tokens x 16 cols; 4 M-tiles x 8 K-steps of 16x16x32.
__global__ __launch_bounds__(128) void out_kernel(
    const float* __restrict__ x, const float* __restrict__ w2s,
    const float* __restrict__ b2s, const float* __restrict__ pw,
    const int* __restrict__ order, const int* __restrict__ spc,
    float* __restrict__ out)
{
    __shared__ unsigned short xs[TILE][DIM];   // bf16, XOR-swizzled 16B granules (32 KiB)
    __shared__ int ord[TILE];
    __shared__ int pcs[TILE];

    int tileId = blockIdx.x >> 3;
    int c0 = (blockIdx.x & 7) * 32;
    int wv = threadIdx.x >> 6;     // 0..1
    int lane = threadIdx.x & 63;
    int colBase = c0 + wv * 16;

    if (threadIdx.x < TILE) {
        int s = tileId * TILE + threadIdx.x;
        ord[threadIdx.x] = order[s];
        pcs[threadIdx.x] = spc[s];
    }
    __syncthreads();

    // stage x rows (sorted) as bf16, swizzled: element d -> granule (d>>3)^(row&7)
    for (int r = wv * 32; r < wv * 32 + 32; ++r) {
        int tok = ord[r];
        float4 v = *reinterpret_cast<const float4*>(x + (size_t)tok * DIM + lane * 4);
        int gs = (lane >> 1) ^ (r & 7);
        ushort4 pk = make_ushort4(f2bf(v.x), f2bf(v.y), f2bf(v.z), f2bf(v.w));
        *reinterpret_cast<ushort4*>(&xs[r][(gs << 3) + (lane & 1) * 4]) = pk;
    }
    __syncthreads();

    int myPc = pcs[lane];
    int rowHi = lane >> 4;

    f32x4 Oacc[4];
    #pragma unroll
    for (int m = 0; m < 4; ++m) Oacc[m] = (f32x4){0.f, 0.f, 0.f, 0.f};

    for (int lvl = 0; lvl < NLEV; ++lvl) {
        int shift = NLEV - lvl;
        int keyl = myPc >> shift;
        int prevKey = __shfl(keyl, (lane + 63) & 63);
        unsigned long long bmask = __ballot((lane == 0) || (prevKey != keyl));

        int s = 0;
        while (s < TILE) {
            unsigned long long rest = (s < 63) ? (bmask >> (s + 1)) : 0ULL;
            int e = rest ? (s + __ffsll(rest)) : TILE;
            int node = __shfl(keyl, s) - 1;

            const float* w2n = w2s + (size_t)node * DIM * DIM;
            f32x4 acc[4];
            #pragma unroll
            for (int m = 0; m < 4; ++m) acc[m] = (f32x4){0.f, 0.f, 0.f, 0.f};

            #pragma unroll
            for (int ks = 0; ks < 8; ++ks) {
                // B fragment: lane -> col = colBase+(lane&15), k = ks*32+(lane>>4)*8+i
                int col = colBase + (lane & 15);
                int kb = ks * 32 + (lane >> 4) * 8;
                const float* wp = w2n + (size_t)kb * DIM + col;
                bf16x8 bfrag;
                #pragma unroll
                for (int i = 0; i < 8; ++i) bfrag[i] = (short)f2bf(wp[(size_t)i * DIM]);

                #pragma unroll
                for (int m = 0; m < 4; ++m) {
                    int row = m * 16 + (lane & 15);
                    int g = ks * 4 + (lane >> 4);
                    int gsw = g ^ (row & 7);
                    bf16x8 afrag = *reinterpret_cast<const bf16x8*>(&xs[row][gsw << 3]);
                    acc[m] = __builtin_amdgcn_mfma_f32_16x16x32_bf16(afrag, bfrag, acc[m], 0, 0, 0);
                }
            }

            float bias = b2s[(size_t)node * DIM + colBase + (lane & 15)];
            #pragma unroll
            for (int m = 0; m < 4; ++m) {
                #pragma unroll
                for (int j = 0; j < 4; ++j) {
                    int row = m * 16 + rowHi * 4 + j;
                    float w = 0.0f;
                    if (row >= s && row < e) {
                        int tok = ord[row];
                        w = pw[(size_t)tok * NLEV + lvl];
                    }
                    Oacc[m][j] += w * (acc[m][j] + bias);
                }
            }
            s = e;
        }
    }

    #pragma unroll
    for (int m = 0; m < 4; ++m) {
        #pragma unroll
        for (int j = 0; j < 4; ++j) {
            int row = m * 16 + rowHi * 4 + j;
            int tok = ord[row];
            out[(size_t)tok * DIM + colBase + (lane & 15)] = Oacc[m][j];
        }
    }
}

extern "C" void kernel_launch(void* const* d_in, const int* in_sizes, int n_in,
                              void* d_out, int out_size, void* d_ws, size_t ws_size,
                              hipStream_t stream) {
    const float* x   = (const float*)d_in[0];
    const float* w1s = (const float*)d_in[1];
    const float* b1s = (const float*)d_in[2];
    const float* w2s = (const float*)d_in[3];
    const float* b2s = (const float*)d_in[4];
    float* out = (float*)d_out;

    float* pw  = (float*)d_ws;                 // 2048*8 f32
    int* pc    = (int*)(pw + T_TOKENS * NLEV); // 2048
    int* order = pc + T_TOKENS;                // 2048
    int* spc   = order + T_TOKENS;             // 2048

    route_kernel<<<T_TOKENS / 4, 256, 0, stream>>>(x, w1s, b1s, pw, pc);
    sort_kernel<<<1, 256, 0, stream>>>(pc, order, spc);
    out_kernel<<<NTILES * 8, 128, 0, stream>>>(x, w2s, b2s, pw, order, spc, out);
}